// Round 15
// baseline (188.597 us; speedup 1.0000x reference)
//
#include <hip/hip_runtime.h>
#include <hip/hip_bf16.h>

#define NB 8
#define NS 1024
#define ND 768
#define NH 12
#define NC 64
#define NEG 0.2f
#define NBUK 128

typedef __attribute__((ext_vector_type(8))) short bf16x8;
typedef __attribute__((ext_vector_type(4))) float f32x4;

static __device__ __forceinline__ float bf2f(unsigned short u) {
    union { float f; unsigned int i; } v; v.i = ((unsigned int)u) << 16; return v.f;
}
static __device__ __forceinline__ unsigned short f2bf(float f) {
    union { float f; unsigned int i; } v; v.f = f;
    unsigned int r = v.i + 0x7FFFu + ((v.i >> 16) & 1u);
    return (unsigned short)(r >> 16);
}

static __device__ __forceinline__ void gload16(const unsigned short* g, unsigned short* l) {
    __builtin_amdgcn_global_load_lds((const __attribute__((address_space(1))) void*)g,
                                     (__attribute__((address_space(3))) void*)l, 16, 0, 0);
}

// bijective XCD-chunk swizzle (m204)
static __device__ __forceinline__ int swz_bid(int orig, int nwg) {
    int q = nwg >> 3, r = nwg & 7;
    int xcd = orig & 7, idx = orig >> 3;
    return (xcd < r ? xcd * (q + 1) : r * (q + 1) + (xcd - r) * q) + idx;
}

// ---------------- prep: weight transposes + fp32->bf16 conversions + bias_tot ----------------
__global__ __launch_bounds__(256) void k_prep(const float* __restrict__ hs, const float* __restrict__ to,
                                              const float* __restrict__ Wp, const float* __restrict__ Wg,
                                              const float* __restrict__ Wf, const float* __restrict__ bp,
                                              const float* __restrict__ bfu,
                                              unsigned short* __restrict__ h_bf, unsigned short* __restrict__ t_bf,
                                              unsigned short* __restrict__ Wp_bf, unsigned short* __restrict__ WgT,
                                              unsigned short* __restrict__ WfT, float* __restrict__ bias_tot,
                                              int n1, int n2) {
    const int NT1 = (ND / 32) * (3 * ND / 32);   // 1728 transpose tiles
    const int NT2 = (ND * 8) / 256;              // 24 bias blocks
    int blk = blockIdx.x, t = threadIdx.x;
    if (blk < NT1) {
        __shared__ float tile[32][33];
        int bx = blk % (ND / 32), by = blk / (ND / 32);
        const float* src; unsigned short* dst; int K, k0;
        if (by < ND / 32) { src = Wg; dst = WgT; K = ND; k0 = by * 32; }
        else { src = Wf; dst = WfT; K = 2 * ND; k0 = (by - ND / 32) * 32; }
        int n0 = bx * 32;
        int r = t >> 3, c4 = (t & 7) * 4;
        float4 v = *reinterpret_cast<const float4*>(src + (size_t)(k0 + r) * ND + n0 + c4);
        tile[r][c4] = v.x; tile[r][c4 + 1] = v.y; tile[r][c4 + 2] = v.z; tile[r][c4 + 3] = v.w;
        __syncthreads();
        ushort4 o;
        o.x = f2bf(tile[c4][r]); o.y = f2bf(tile[c4 + 1][r]);
        o.z = f2bf(tile[c4 + 2][r]); o.w = f2bf(tile[c4 + 3][r]);
        *reinterpret_cast<ushort4*>(dst + (size_t)(n0 + r) * K + k0 + c4) = o;
    } else if (blk < NT1 + NT2) {
        int gid = (blk - NT1) * 256 + t;
        int c = gid >> 3, sl = gid & 7;
        float acc = 0.f;
        int k0 = sl * 96;
#pragma unroll 8
        for (int k = k0; k < k0 + 96; k++) acc += bp[k] * Wf[(size_t)(ND + k) * ND + c];
        acc += __shfl_down(acc, 1, 64);
        acc += __shfl_down(acc, 2, 64);
        acc += __shfl_down(acc, 4, 64);
        if (sl == 0) bias_tot[c] = acc + bfu[c];
    } else {
        int gid = (blk - NT1 - NT2) * 256 + t;
        const float* s; unsigned short* d; int i;
        if (gid < n1) { s = hs; d = h_bf; i = gid; }
        else if (gid < 2 * n1) { s = to; d = t_bf; i = gid - n1; }
        else { s = Wp; d = Wp_bf; i = gid - 2 * n1; if (i >= n2) return; }
        i *= 4;
        float4 v = *reinterpret_cast<const float4*>(s + i);
        ushort4 o;
        o.x = f2bf(v.x); o.y = f2bf(v.y); o.z = f2bf(v.z); o.w = f2bf(v.w);
        *reinterpret_cast<ushort4*>(d + i) = o;
    }
}

// ---------------- direct bucket-sum: branch-free scatter-accumulate into LDS ----------------
// grid (4, NBH): block = (channel-quarter cq, bh). Scans all 1024 rows; every row hits
// exactly one bucket. No sort, no pack, no serial FP chain (iterations independent).
__global__ __launch_bounds__(256) void k_psum(const unsigned short* __restrict__ x_bf,
                                              const float* __restrict__ a_src,
                                              float* __restrict__ P,
                                              float* __restrict__ zb,
                                              float* __restrict__ smax_g,
                                              float2* __restrict__ bparam) {
    int cq = blockIdx.x, bh = blockIdx.y, t = threadIdx.x;
    int b = bh / NH, h = bh % NH;
    int w = t >> 6, lane = t & 63;
    int c = lane & 15, rr = lane >> 4;
    __shared__ float v[1024];
    __shared__ float red[256];
    __shared__ float Pl1[NBUK * 17], Pl2[NBUK * 17];
    __shared__ float zl1[NBUK], zl2[NBUK];
    for (int i = t; i < 1024; i += 256) v[i] = a_src[(size_t)bh * 1024 + i];
    for (int i = t; i < NBUK * 17; i += 256) { Pl1[i] = 0.f; Pl2[i] = 0.f; }
    if (t < NBUK) { zl1[t] = 0.f; zl2[t] = 0.f; }
    __syncthreads();
    float lm = -1e30f, ln = 1e30f;
    for (int i = t; i < 1024; i += 256) { lm = fmaxf(lm, v[i]); ln = fminf(ln, v[i]); }
    red[t] = lm; __syncthreads();
    for (int s = 128; s > 0; s >>= 1) { if (t < s) red[t] = fmaxf(red[t], red[t + s]); __syncthreads(); }
    float mx = red[0]; __syncthreads();
    red[t] = ln; __syncthreads();
    for (int s = 128; s > 0; s >>= 1) { if (t < s) red[t] = fminf(red[t], red[t + s]); __syncthreads(); }
    float mn = red[0]; __syncthreads();
    float scale = (float)NBUK / fmaxf(mx - mn, 1e-20f);
    const unsigned short* xb = x_bf + (size_t)b * NS * ND + h * 64 + cq * 16 + c;
#pragma unroll 4
    for (int it = 0; it < 64; it++) {
        int j = w * 256 + it * 4 + rr;
        float vj = v[j];
        int bk = min(max((int)((vj - mn) * scale), 0), NBUK - 1);
        float u = vj - mx;
        float e1 = __expf(u), e2 = __expf(0.2f * u);
        float xv = bf2f(xb[(size_t)j * ND]);
        atomicAdd(&Pl1[bk * 17 + c], e1 * xv);
        atomicAdd(&Pl2[bk * 17 + c], e2 * xv);
        if (cq == 0 && c == 0) { atomicAdd(&zl1[bk], e1); atomicAdd(&zl2[bk], e2); }
    }
    __syncthreads();
    for (int i = t; i < NBUK * 16; i += 256) {
        int bk = i >> 4, cc = i & 15;
        size_t o = ((size_t)(bh * NBUK + bk) * 2) * 64 + cq * 16 + cc;
        P[o] = Pl1[bk * 17 + cc];
        P[o + 64] = Pl2[bk * 17 + cc];
    }
    if (cq == 0) {
        if (t < NBUK) {
            zb[(size_t)(bh * NBUK + t) * 2] = zl1[t];       // RAW sums; scanned in k_bpref
            zb[(size_t)(bh * NBUK + t) * 2 + 1] = zl2[t];
        }
        if (t == 0) { smax_g[bh] = mx; bparam[bh] = make_float2(mn, scale); }
    }
}

// ---------------- inclusive prefix over buckets: vectors P (in-place) + scalars zb ----------------
__global__ __launch_bounds__(256) void k_bpref(float* __restrict__ P, float* __restrict__ zb) {
    int bh = blockIdx.x, t = threadIdx.x, w = t >> 6, lane = t & 63;
    __shared__ float segV[4][2][64];
    __shared__ float zsh1[NBUK], zsh2[NBUK];
    if (t < NBUK) {
        zsh1[t] = zb[(size_t)(bh * NBUK + t) * 2];
        zsh2[t] = zb[(size_t)(bh * NBUK + t) * 2 + 1];
    }
    __syncthreads();
    for (int off = 1; off < NBUK; off <<= 1) {
        float x1 = (t >= off && t < NBUK) ? zsh1[t - off] : 0.f;
        float x2 = (t >= off && t < NBUK) ? zsh2[t - off] : 0.f;
        __syncthreads();
        if (t < NBUK) { zsh1[t] += x1; zsh2[t] += x2; }
        __syncthreads();
    }
    if (t < NBUK) {
        zb[(size_t)(bh * NBUK + t) * 2] = zsh1[t];
        zb[(size_t)(bh * NBUK + t) * 2 + 1] = zsh2[t];
    }
    size_t base = (size_t)bh * NBUK;
    float V1 = 0.f, V2 = 0.f;
    for (int g = 0; g < 4; ++g) {
        float a1[8], a2[8];
#pragma unroll
        for (int r = 0; r < 8; r++) {
            size_t o = ((base + w * 32 + g * 8 + r) * 2) * 64 + lane;
            a1[r] = P[o]; a2[r] = P[o + 64];
        }
#pragma unroll
        for (int r = 0; r < 8; r++) { V1 += a1[r]; a1[r] = V1; V2 += a2[r]; a2[r] = V2; }
#pragma unroll
        for (int r = 0; r < 8; r++) {
            size_t o = ((base + w * 32 + g * 8 + r) * 2) * 64 + lane;
            P[o] = a1[r]; P[o + 64] = a2[r];
        }
    }
    segV[w][0][lane] = V1; segV[w][1][lane] = V2;
    __syncthreads();
    if (w > 0) {
        float O1 = 0.f, O2 = 0.f;
        for (int w2 = 0; w2 < w; w2++) { O1 += segV[w2][0][lane]; O2 += segV[w2][1][lane]; }
        for (int g = 0; g < 4; ++g) {
            float a1[8], a2[8];
#pragma unroll
            for (int r = 0; r < 8; r++) {
                size_t o = ((base + w * 32 + g * 8 + r) * 2) * 64 + lane;
                a1[r] = P[o]; a2[r] = P[o + 64];
            }
#pragma unroll
            for (int r = 0; r < 8; r++) {
                size_t o = ((base + w * 32 + g * 8 + r) * 2) * 64 + lane;
                P[o] = a1[r] + O1; P[o + 64] = a2[r] + O2;
            }
        }
    }
}

// ---------------- apply: rounded-bucket-edge cutoff, pure prefix combine ----------------
__global__ __launch_bounds__(256) void k_apply3(const float* __restrict__ P,
                                                const float* __restrict__ zb,
                                                const float* __restrict__ a_dst,
                                                const float* __restrict__ smax_g,
                                                const float2* __restrict__ bparam,
                                                const float* __restrict__ b_gat,
                                                unsigned short* __restrict__ gat) {
    int bh = blockIdx.y, t = threadIdx.x, w = t >> 6, lane = t & 63;
    int b = bh / NH, h = bh % NH;
    float sm = smax_g[bh];
    float2 bp_ = bparam[bh];
    float mn = bp_.x, scale = bp_.y;
    size_t pb = (size_t)bh * NBUK;
    float T1 = P[((pb + NBUK - 1) * 2) * 64 + lane];
    float z1tot = zb[(pb + NBUK - 1) * 2];
    float bias = b_gat[h * 64 + lane];
#pragma unroll
    for (int q = 0; q < 8; q++) {
        int i = blockIdx.x * 32 + w * 8 + q;
        float d = a_dst[(size_t)bh * 1024 + i];
        float dm = d + sm;
        float m = dm > 0.f ? dm : NEG * dm;
        float c1 = __expf(dm - m);
        float c2 = __expf(NEG * dm - m);
        int e = (int)floorf((-d - mn) * scale + 0.5f);
        e = min(max(e, 0), NBUK);
        float P1f = 0.f, P2f = 0.f, z1f = 0.f, z2f = 0.f;
        if (e > 0) {
            size_t o = ((pb + e - 1) * 2) * 64 + lane;
            P1f = P[o]; P2f = P[o + 64];
            z1f = zb[(pb + e - 1) * 2];
            z2f = zb[(pb + e - 1) * 2 + 1];
        }
        float num = c1 * (T1 - P1f) + c2 * P2f;
        float Z = c1 * (z1tot - z1f) + c2 * z2f;
        gat[((size_t)(b * NS + i)) * ND + h * 64 + lane] = f2bf(num / Z + bias);
    }
}

// ---------------- GEMM core: 64x128 tile, BK=64, XOR chunk-swizzle, dbuf LDS ----------------
// T4 counted-vmcnt pipeline (R12-verified): wait vmcnt(6), raw s_barrier, compute, barrier, restage.
template <bool OUT_BF16, bool BIAS, bool DUAL, bool ATT>
static __device__ __forceinline__ void gemm_body(
    const unsigned short* __restrict__ A1, const unsigned short* __restrict__ B1,
    int lda1, int ldb1,
    const unsigned short* __restrict__ A2, const unsigned short* __restrict__ B2,
    int lda2, int ldb2,
    const float* __restrict__ bias, void* __restrict__ Cout,
    int m0, int n0, int N, int K,
    unsigned short* sA, unsigned short* sB,
    const float* __restrict__ att_src, const float* __restrict__ att_dst,
    float* __restrict__ a_src, float* __restrict__ a_dst) {
    int t = threadIdx.x, wave = t >> 6, lane = t & 63;
    int lr = lane & 15, kq = lane >> 4;
    int srow = t >> 3;                         // 0..31 staging row
    int scol = ((t & 7) ^ (srow & 7)) * 8;     // inverse-swizzled source chunk (shorts)
    int cs0 = ((kq) ^ (lr & 7)) * 8;           // kk=0 read chunk
    int cs1 = ((4 + kq) ^ (lr & 7)) * 8;       // kk=1 read chunk
    const int kh = K >> 6;
    const int nsteps = (DUAL ? 2 : 1) * kh;
    f32x4 acc[4][2] = {};

    auto STAGE = [&](int s, int buf) {
        const unsigned short* A; const unsigned short* Bt; int lda, ldb, k0;
        if (DUAL && s >= kh) { A = A2; Bt = B2; lda = lda2; ldb = ldb2; k0 = (s - kh) << 6; }
        else { A = A1; Bt = B1; lda = lda1; ldb = ldb1; k0 = s << 6; }
        const unsigned short* gA = A + (size_t)(m0 + srow) * lda + scol + k0;
        const unsigned short* gB = Bt + (size_t)(n0 + srow) * ldb + scol + k0;
        unsigned short* dA = sA + buf * 4096 + t * 8;
        unsigned short* dB = sB + buf * 8192 + t * 8;
        gload16(gA, dA);
        gload16(gA + (size_t)32 * lda, dA + 2048);
        gload16(gB, dB);
        gload16(gB + (size_t)32 * ldb, dB + 2048);
        gload16(gB + (size_t)64 * ldb, dB + 4096);
        gload16(gB + (size_t)96 * ldb, dB + 6144);
    };
    auto COMPUTE = [&](int cur) {
        unsigned short* cA = sA + cur * 4096;
        unsigned short* cB = sB + cur * 8192;
        bf16x8 a0[4], a1v[4], b0[2], b1v[2];
#pragma unroll
        for (int m = 0; m < 4; m++) {
            a0[m]  = *reinterpret_cast<bf16x8*>(&cA[(m * 16 + lr) * 64 + cs0]);
            a1v[m] = *reinterpret_cast<bf16x8*>(&cA[(m * 16 + lr) * 64 + cs1]);
        }
#pragma unroll
        for (int n = 0; n < 2; n++) {
            b0[n]  = *reinterpret_cast<bf16x8*>(&cB[(wave * 32 + n * 16 + lr) * 64 + cs0]);
            b1v[n] = *reinterpret_cast<bf16x8*>(&cB[(wave * 32 + n * 16 + lr) * 64 + cs1]);
        }
#pragma unroll
        for (int m = 0; m < 4; m++)
#pragma unroll
            for (int n = 0; n < 2; n++) {
                acc[m][n] = __builtin_amdgcn_mfma_f32_16x16x32_bf16(a0[m], b0[n], acc[m][n], 0, 0, 0);
                acc[m][n] = __builtin_amdgcn_mfma_f32_16x16x32_bf16(a1v[m], b1v[n], acc[m][n], 0, 0, 0);
            }
    };

    STAGE(0, 0);
    STAGE(1, 1);
    for (int s = 0; s < nsteps - 1; s++) {
        int cur = s & 1;
        asm volatile("s_waitcnt vmcnt(6)" ::: "memory");   // prior stage landed; 6 in flight
        __builtin_amdgcn_s_barrier();
        __builtin_amdgcn_sched_barrier(0);
        COMPUTE(cur);
        __builtin_amdgcn_sched_barrier(0);
        __builtin_amdgcn_s_barrier();                       // all waves done reading buf[cur]
        if (s + 2 < nsteps) STAGE(s + 2, cur);              // overwrite buf[cur]
    }
    asm volatile("s_waitcnt vmcnt(0)" ::: "memory");
    __builtin_amdgcn_s_barrier();
    __builtin_amdgcn_sched_barrier(0);
    COMPUTE((nsteps - 1) & 1);

    int rg = kq * 4;
#pragma unroll
    for (int m = 0; m < 4; m++) {
#pragma unroll
        for (int n = 0; n < 2; n++) {
            int col = n0 + wave * 32 + n * 16 + lr;
            float bv = BIAS ? bias[col] : 0.0f;
#pragma unroll
            for (int r = 0; r < 4; r++) {
                int row = m0 + m * 16 + rg + r;
                float v = acc[m][n][r] + bv;
                if (OUT_BF16) {
                    ((unsigned short*)Cout)[(size_t)row * N + col] = f2bf(v);
                } else {
                    ((float*)Cout)[(size_t)row * N + col] = v;
                }
            }
        }
    }

    if (ATT) {
        __syncthreads();   // all waves done with sA before scratch reuse
        float ds_[4][4] = {}, dd_[4][4] = {};
#pragma unroll
        for (int n = 0; n < 2; n++) {
            int colg = n0 + wave * 32 + n * 16 + lr;
            float as_v = att_src[colg];
            float ad_v = att_dst[colg];
#pragma unroll
            for (int m = 0; m < 4; m++)
#pragma unroll
                for (int r = 0; r < 4; r++) {
                    ds_[m][r] = fmaf(acc[m][n][r], as_v, ds_[m][r]);
                    dd_[m][r] = fmaf(acc[m][n][r], ad_v, dd_[m][r]);
                }
        }
#pragma unroll
        for (int off = 1; off <= 8; off <<= 1)
#pragma unroll
            for (int m = 0; m < 4; m++)
#pragma unroll
                for (int r = 0; r < 4; r++) {
                    ds_[m][r] += __shfl_xor(ds_[m][r], off, 64);
                    dd_[m][r] += __shfl_xor(dd_[m][r], off, 64);
                }
        float* red = (float*)sA;   // scratch, safe post-loop
        if (lr == 0) {
#pragma unroll
            for (int m = 0; m < 4; m++)
#pragma unroll
                for (int r = 0; r < 4; r++) {
                    int rl = m * 16 + kq * 4 + r;
                    red[wave * 64 + rl] = ds_[m][r];
                    red[256 + wave * 64 + rl] = dd_[m][r];
                }
        }
        __syncthreads();
        if (t < 128) {
            int hb = t >> 6, rl = t & 63;
            float vs = red[(hb * 2) * 64 + rl] + red[(hb * 2 + 1) * 64 + rl];
            float vd = red[256 + (hb * 2) * 64 + rl] + red[256 + (hb * 2 + 1) * 64 + rl];
            int grow = m0 + rl;
            int b = grow >> 10, sdx = grow & 1023;
            int head = (n0 >> 6) + hb;
            a_src[((size_t)b * NH + head) * NS + sdx] = vs;
            a_dst[((size_t)b * NH + head) * NS + sdx] = vd;
        }
    }
}

// two independent bf16-out GEMMs in one grid (gemm1 [+attn dots] + Wcomb)
__global__ __launch_bounds__(256) void k_gemm_pair(
    const unsigned short* __restrict__ Aa, const unsigned short* __restrict__ Ba,
    unsigned short* __restrict__ Ca, int NBna, int Na, int Ka, int lda_a, int ldb_a, int nwg_a,
    const unsigned short* __restrict__ Ab, const unsigned short* __restrict__ Bb,
    unsigned short* __restrict__ Cb, int NBnb, int Nb, int Kb, int lda_b, int ldb_b,
    const float* __restrict__ att_src, const float* __restrict__ att_dst,
    float* __restrict__ a_src, float* __restrict__ a_dst) {
    __shared__ alignas(16) unsigned short sA[2 * 64 * 64];
    __shared__ alignas(16) unsigned short sB[2 * 128 * 64];
    int wg = swz_bid(blockIdx.x, gridDim.x);
    if (wg < nwg_a) {
        gemm_body<true, false, false, true>(Aa, Ba, lda_a, ldb_a, nullptr, nullptr, 0, 0, nullptr,
                                            Ca, (wg / NBna) * 64, (wg % NBna) * 128, Na, Ka, sA, sB,
                                            att_src, att_dst, a_src, a_dst);
    } else {
        wg -= nwg_a;
        gemm_body<true, false, false, false>(Ab, Bb, lda_b, ldb_b, nullptr, nullptr, 0, 0, nullptr,
                                             Cb, (wg / NBnb) * 64, (wg % NBnb) * 128, Nb, Kb, sA, sB,
                                             nullptr, nullptr, nullptr, nullptr);
    }
}

// dual accumulating GEMM with fp32 out + bias
__global__ __launch_bounds__(256) void k_gemm_dual(
    const unsigned short* __restrict__ A1, const unsigned short* __restrict__ B1,
    const unsigned short* __restrict__ A2, const unsigned short* __restrict__ B2,
    const float* __restrict__ bias, float* __restrict__ out,
    int NBn, int N, int K, int lda, int ldb1, int ldb2) {
    __shared__ alignas(16) unsigned short sA[2 * 64 * 64];
    __shared__ alignas(16) unsigned short sB[2 * 128 * 64];
    int wg = swz_bid(blockIdx.x, gridDim.x);
    gemm_body<false, true, true, false>(A1, B1, lda, ldb1, A2, B2, lda, ldb2, bias,
                                        out, (wg / NBn) * 64, (wg % NBn) * 128, N, K, sA, sB,
                                        nullptr, nullptr, nullptr, nullptr);
}

extern "C" void kernel_launch(void* const* d_in, const int* in_sizes, int n_in,
                              void* d_out, int out_size, void* d_ws, size_t ws_size,
                              hipStream_t stream) {
    const float* hs  = (const float*)d_in[0];
    const float* to  = (const float*)d_in[1];
    const float* Wg  = (const float*)d_in[2];
    const float* asv = (const float*)d_in[3];
    const float* adv = (const float*)d_in[4];
    const float* bg  = (const float*)d_in[5];
    const float* Wp  = (const float*)d_in[6];
    const float* bp  = (const float*)d_in[7];
    const float* Wf  = (const float*)d_in[8];
    const float* bfu = (const float*)d_in[9];
    float* out = (float*)d_out;

    char* ws = (char*)d_ws;
    size_t off = 0;
    auto alloc = [&](size_t bytes) -> void* {
        void* p = ws + off;
        off = (off + bytes + 255) & ~(size_t)255;
        return p;
    };
    const size_t NBSD = (size_t)NB * NS * ND;
    const int NBH = NB * NH;
    unsigned short* h_bf   = (unsigned short*)alloc(NBSD * 2);  // later reused as gat_bf
    unsigned short* x_bf   = (unsigned short*)alloc(NBSD * 2);
    unsigned short* t_bf   = (unsigned short*)alloc(NBSD * 2);
    unsigned short* WgT    = (unsigned short*)alloc((size_t)ND * ND * 2);
    unsigned short* Wp_bf  = (unsigned short*)alloc((size_t)ND * ND * 2);
    unsigned short* WfT    = (unsigned short*)alloc((size_t)2 * ND * ND * 2);
    unsigned short* WcombT = (unsigned short*)alloc((size_t)ND * ND * 2);
    float*  bias_tot = (float*)alloc((size_t)ND * 4);
    float*  a_src = (float*)alloc((size_t)NBH * NS * 4);
    float*  a_dst = (float*)alloc((size_t)NBH * NS * 4);
    float*  P     = (float*)alloc((size_t)NBH * NBUK * 2 * 64 * 4);
    float*  zb    = (float*)alloc((size_t)NBH * NBUK * 2 * 4);
    float*  smaxb = (float*)alloc((size_t)NBH * 4);
    float2* bparam = (float2*)alloc((size_t)NBH * 8);

    int n1 = (int)NBSD / 4, n2 = ND * ND / 4;
    const int NT1 = (ND / 32) * (3 * ND / 32);
    const int NT2 = (ND * 8) / 256;
    const int NT3 = (2 * n1 + n2 + 255) / 256;
    k_prep<<<NT1 + NT2 + NT3, 256, 0, stream>>>(hs, to, Wp, Wg, Wf, bp, bfu,
                                                h_bf, t_bf, Wp_bf, WgT, WfT, bias_tot, n1, n2);

    // gemm1 (x = hs@W_gat, + attn dots) ; Wcomb: WcombT = (Wp @ Wf_bot)^T  — one grid, n-fastest
    int nwg1 = (NB * NS / 64) * (ND / 128);          // 576
    int nwgW = (ND / 64) * (ND / 128);               // 72
    k_gemm_pair<<<nwg1 + nwgW, 256, 0, stream>>>(
        h_bf, WgT, x_bf, ND / 128, ND, ND, ND, ND, nwg1,
        WfT + ND, Wp_bf, WcombT, ND / 128, ND, ND, 2 * ND, ND,
        asv, adv, a_src, a_dst);

    // direct bucket-sums (branch-free LDS scatter-accumulate; raw z written, scanned in bpref)
    k_psum<<<dim3(4, NBH), 256, 0, stream>>>(x_bf, a_src, P, zb, smaxb, bparam);
    k_bpref<<<NBH, 256, 0, stream>>>(P, zb);

    unsigned short* gat_bf = h_bf;
    k_apply3<<<dim3(NS / 32, NBH), 256, 0, stream>>>(P, zb, a_dst, smaxb, bparam, bg, gat_bf);

    // out = t @ Wf_top + gat @ Wcomb + bias_tot
    k_gemm_dual<<<(NB * NS / 64) * (ND / 128), 256, 0, stream>>>(
        t_bf, WfT, gat_bf, WcombT, bias_tot, out, ND / 128, ND, ND, ND, 2 * ND, ND);
}

// Round 16
// 117.994 us; speedup vs baseline: 1.5984x; 1.5984x over previous
//
#include <hip/hip_runtime.h>
#include <hip/hip_bf16.h>

#define NB 8
#define NS 1024
#define ND 768
#define NH 12
#define NC 64
#define NEG 0.2f
#define NBUK 128

typedef __attribute__((ext_vector_type(8))) short bf16x8;
typedef __attribute__((ext_vector_type(4))) float f32x4;

static __device__ __forceinline__ float bf2f(unsigned short u) {
    union { float f; unsigned int i; } v; v.i = ((unsigned int)u) << 16; return v.f;
}
static __device__ __forceinline__ unsigned short f2bf(float f) {
    union { float f; unsigned int i; } v; v.f = f;
    unsigned int r = v.i + 0x7FFFu + ((v.i >> 16) & 1u);
    return (unsigned short)(r >> 16);
}

static __device__ __forceinline__ void gload16(const unsigned short* g, unsigned short* l) {
    __builtin_amdgcn_global_load_lds((const __attribute__((address_space(1))) void*)g,
                                     (__attribute__((address_space(3))) void*)l, 16, 0, 0);
}

// bijective XCD-chunk swizzle (m204)
static __device__ __forceinline__ int swz_bid(int orig, int nwg) {
    int q = nwg >> 3, r = nwg & 7;
    int xcd = orig & 7, idx = orig >> 3;
    return (xcd < r ? xcd * (q + 1) : r * (q + 1) + (xcd - r) * q) + idx;
}

// ---------------- prep: weight transposes + fp32->bf16 conversions + bias_tot ----------------
__global__ __launch_bounds__(256) void k_prep(const float* __restrict__ hs, const float* __restrict__ to,
                                              const float* __restrict__ Wp, const float* __restrict__ Wg,
                                              const float* __restrict__ Wf, const float* __restrict__ bp,
                                              const float* __restrict__ bfu,
                                              unsigned short* __restrict__ h_bf, unsigned short* __restrict__ t_bf,
                                              unsigned short* __restrict__ Wp_bf, unsigned short* __restrict__ WgT,
                                              unsigned short* __restrict__ WfT, float* __restrict__ bias_tot,
                                              int n1, int n2) {
    const int NT1 = (ND / 32) * (3 * ND / 32);   // 1728 transpose tiles
    const int NT2 = (ND * 8) / 256;              // 24 bias blocks
    int blk = blockIdx.x, t = threadIdx.x;
    if (blk < NT1) {
        __shared__ float tile[32][33];
        int bx = blk % (ND / 32), by = blk / (ND / 32);
        const float* src; unsigned short* dst; int K, k0;
        if (by < ND / 32) { src = Wg; dst = WgT; K = ND; k0 = by * 32; }
        else { src = Wf; dst = WfT; K = 2 * ND; k0 = (by - ND / 32) * 32; }
        int n0 = bx * 32;
        int r = t >> 3, c4 = (t & 7) * 4;
        float4 v = *reinterpret_cast<const float4*>(src + (size_t)(k0 + r) * ND + n0 + c4);
        tile[r][c4] = v.x; tile[r][c4 + 1] = v.y; tile[r][c4 + 2] = v.z; tile[r][c4 + 3] = v.w;
        __syncthreads();
        ushort4 o;
        o.x = f2bf(tile[c4][r]); o.y = f2bf(tile[c4 + 1][r]);
        o.z = f2bf(tile[c4 + 2][r]); o.w = f2bf(tile[c4 + 3][r]);
        *reinterpret_cast<ushort4*>(dst + (size_t)(n0 + r) * K + k0 + c4) = o;
    } else if (blk < NT1 + NT2) {
        int gid = (blk - NT1) * 256 + t;
        int c = gid >> 3, sl = gid & 7;
        float acc = 0.f;
        int k0 = sl * 96;
#pragma unroll 8
        for (int k = k0; k < k0 + 96; k++) acc += bp[k] * Wf[(size_t)(ND + k) * ND + c];
        acc += __shfl_down(acc, 1, 64);
        acc += __shfl_down(acc, 2, 64);
        acc += __shfl_down(acc, 4, 64);
        if (sl == 0) bias_tot[c] = acc + bfu[c];
    } else {
        int gid = (blk - NT1 - NT2) * 256 + t;
        const float* s; unsigned short* d; int i;
        if (gid < n1) { s = hs; d = h_bf; i = gid; }
        else if (gid < 2 * n1) { s = to; d = t_bf; i = gid - n1; }
        else { s = Wp; d = Wp_bf; i = gid - 2 * n1; if (i >= n2) return; }
        i *= 4;
        float4 v = *reinterpret_cast<const float4*>(s + i);
        ushort4 o;
        o.x = f2bf(v.x); o.y = f2bf(v.y); o.z = f2bf(v.z); o.w = f2bf(v.w);
        *reinterpret_cast<ushort4*>(d + i) = o;
    }
}

// ---------------- counting sort into NBUK buckets + fused z-prefix (once per bh) ----------------
__global__ __launch_bounds__(256) void k_bucket(const float* __restrict__ a_src,
                                                float4* __restrict__ pack,
                                                int* __restrict__ bstart,
                                                float* __restrict__ smax_g,
                                                float2* __restrict__ bparam,
                                                float* __restrict__ zb) {
    int bh = blockIdx.x, t = threadIdx.x;
    __shared__ float v[1024];
    __shared__ int bi[1024];
    __shared__ float red[256];
    __shared__ int cnt[NBUK], pre[NBUK];
    __shared__ float zs1[NBUK], zs2[NBUK];
    for (int i = t; i < 1024; i += 256) v[i] = a_src[(size_t)bh * 1024 + i];
    if (t < NBUK) { cnt[t] = 0; zs1[t] = 0.f; zs2[t] = 0.f; }
    __syncthreads();
    float lm = -1e30f, ln = 1e30f;
    for (int i = t; i < 1024; i += 256) { lm = fmaxf(lm, v[i]); ln = fminf(ln, v[i]); }
    red[t] = lm; __syncthreads();
    for (int s = 128; s > 0; s >>= 1) { if (t < s) red[t] = fmaxf(red[t], red[t + s]); __syncthreads(); }
    float mx = red[0]; __syncthreads();
    red[t] = ln; __syncthreads();
    for (int s = 128; s > 0; s >>= 1) { if (t < s) red[t] = fminf(red[t], red[t + s]); __syncthreads(); }
    float mn = red[0]; __syncthreads();
    float scale = (float)NBUK / fmaxf(mx - mn, 1e-20f);
    for (int i = t; i < 1024; i += 256) {
        int bk = (int)((v[i] - mn) * scale);
        bk = min(max(bk, 0), NBUK - 1);
        bi[i] = bk;
        atomicAdd(&cnt[bk], 1);
    }
    __syncthreads();
    if (t < NBUK) pre[t] = cnt[t];
    __syncthreads();
    for (int off = 1; off < NBUK; off <<= 1) {
        int x = (t >= off && t < NBUK) ? pre[t - off] : 0;
        __syncthreads();
        if (t < NBUK) pre[t] += x;
        __syncthreads();
    }
    if (t < NBUK) {
        int start = pre[t] - cnt[t];
        bstart[bh * (NBUK + 1) + t] = start;
        cnt[t] = start;
    }
    if (t == 0) {
        bstart[bh * (NBUK + 1) + NBUK] = 1024;
        smax_g[bh] = mx;
        bparam[bh] = make_float2(mn, scale);
    }
    __syncthreads();
    for (int i = t; i < 1024; i += 256) {
        int pos = atomicAdd(&cnt[bi[i]], 1);
        float u = v[i] - mx;
        float4 p;
        p.x = u; p.y = __expf(u); p.z = __expf(0.2f * u); p.w = __int_as_float(i);
        pack[(size_t)bh * 1024 + pos] = p;
        atomicAdd(&zs1[bi[i]], p.y);
        atomicAdd(&zs2[bi[i]], p.z);
    }
    __syncthreads();
    for (int off = 1; off < NBUK; off <<= 1) {
        float x1 = (t >= off && t < NBUK) ? zs1[t - off] : 0.f;
        float x2 = (t >= off && t < NBUK) ? zs2[t - off] : 0.f;
        __syncthreads();
        if (t < NBUK) { zs1[t] += x1; zs2[t] += x2; }
        __syncthreads();
    }
    if (t < NBUK) {
        zb[(size_t)(bh * NBUK + t) * 2] = zs1[t];
        zb[(size_t)(bh * NBUK + t) * 2 + 1] = zs2[t];
    }
}

// ---------------- per-bucket vector sums with 4-way ILP (breaks serial gather chain) ----------------
__global__ __launch_bounds__(256) void k_bsum(const unsigned short* __restrict__ x_bf,
                                              const float4* __restrict__ pack,
                                              const int* __restrict__ bstart,
                                              float* __restrict__ P) {
    int grp = blockIdx.x, bh = blockIdx.y;
    int t = threadIdx.x, w = t >> 6, lane = t & 63;
    int b = bh / NH, h = bh % NH;
    const float4* pk = pack + (size_t)bh * 1024;
    const unsigned short* xb = x_bf + (size_t)b * NS * ND + h * 64 + lane;
#pragma unroll
    for (int r = 0; r < 2; r++) {
        int bk = grp * 8 + w * 2 + r;
        int ks = bstart[bh * (NBUK + 1) + bk], ke = bstart[bh * (NBUK + 1) + bk + 1];
        float V1p0 = 0.f, V1p1 = 0.f, V1p2 = 0.f, V1p3 = 0.f;
        float V2p0 = 0.f, V2p1 = 0.f, V2p2 = 0.f, V2p3 = 0.f;
        int k = ks;
        for (; k + 4 <= ke; k += 4) {
            float4 p0 = pk[k], p1 = pk[k + 1], p2 = pk[k + 2], p3 = pk[k + 3];
            float x0 = bf2f(xb[(size_t)__float_as_int(p0.w) * ND]);
            float x1 = bf2f(xb[(size_t)__float_as_int(p1.w) * ND]);
            float x2 = bf2f(xb[(size_t)__float_as_int(p2.w) * ND]);
            float x3 = bf2f(xb[(size_t)__float_as_int(p3.w) * ND]);
            V1p0 = fmaf(p0.y, x0, V1p0); V2p0 = fmaf(p0.z, x0, V2p0);
            V1p1 = fmaf(p1.y, x1, V1p1); V2p1 = fmaf(p1.z, x1, V2p1);
            V1p2 = fmaf(p2.y, x2, V1p2); V2p2 = fmaf(p2.z, x2, V2p2);
            V1p3 = fmaf(p3.y, x3, V1p3); V2p3 = fmaf(p3.z, x3, V2p3);
        }
        for (; k < ke; k++) {
            float4 p = pk[k];
            float xv = bf2f(xb[(size_t)__float_as_int(p.w) * ND]);
            V1p0 = fmaf(p.y, xv, V1p0); V2p0 = fmaf(p.z, xv, V2p0);
        }
        float V1 = (V1p0 + V1p1) + (V1p2 + V1p3);
        float V2 = (V2p0 + V2p1) + (V2p2 + V2p3);
        size_t o = ((size_t)(bh * NBUK + bk) * 2) * 64 + lane;
        P[o] = V1; P[o + 64] = V2;
    }
}

// ---------------- inclusive prefix over buckets for vectors P ----------------
__global__ __launch_bounds__(256) void k_bpref(float* __restrict__ P) {
    int bh = blockIdx.x, t = threadIdx.x, w = t >> 6, lane = t & 63;
    __shared__ float segV[4][2][64];
    size_t base = (size_t)bh * NBUK;
    float V1 = 0.f, V2 = 0.f;
    for (int g = 0; g < 4; ++g) {
        float a1[8], a2[8];
#pragma unroll
        for (int r = 0; r < 8; r++) {
            size_t o = ((base + w * 32 + g * 8 + r) * 2) * 64 + lane;
            a1[r] = P[o]; a2[r] = P[o + 64];
        }
#pragma unroll
        for (int r = 0; r < 8; r++) { V1 += a1[r]; a1[r] = V1; V2 += a2[r]; a2[r] = V2; }
#pragma unroll
        for (int r = 0; r < 8; r++) {
            size_t o = ((base + w * 32 + g * 8 + r) * 2) * 64 + lane;
            P[o] = a1[r]; P[o + 64] = a2[r];
        }
    }
    segV[w][0][lane] = V1; segV[w][1][lane] = V2;
    __syncthreads();
    if (w > 0) {
        float O1 = 0.f, O2 = 0.f;
        for (int w2 = 0; w2 < w; w2++) { O1 += segV[w2][0][lane]; O2 += segV[w2][1][lane]; }
        for (int g = 0; g < 4; ++g) {
            float a1[8], a2[8];
#pragma unroll
            for (int r = 0; r < 8; r++) {
                size_t o = ((base + w * 32 + g * 8 + r) * 2) * 64 + lane;
                a1[r] = P[o]; a2[r] = P[o + 64];
            }
#pragma unroll
            for (int r = 0; r < 8; r++) {
                size_t o = ((base + w * 32 + g * 8 + r) * 2) * 64 + lane;
                P[o] = a1[r] + O1; P[o + 64] = a2[r] + O2;
            }
        }
    }
}

// ---------------- apply: rounded-bucket-edge cutoff, pure prefix combine ----------------
__global__ __launch_bounds__(256) void k_apply3(const float* __restrict__ P,
                                                const float* __restrict__ zb,
                                                const float* __restrict__ a_dst,
                                                const float* __restrict__ smax_g,
                                                const float2* __restrict__ bparam,
                                                const float* __restrict__ b_gat,
                                                unsigned short* __restrict__ gat) {
    int bh = blockIdx.y, t = threadIdx.x, w = t >> 6, lane = t & 63;
    int b = bh / NH, h = bh % NH;
    float sm = smax_g[bh];
    float2 bp_ = bparam[bh];
    float mn = bp_.x, scale = bp_.y;
    size_t pb = (size_t)bh * NBUK;
    float T1 = P[((pb + NBUK - 1) * 2) * 64 + lane];
    float z1tot = zb[(pb + NBUK - 1) * 2];
    float bias = b_gat[h * 64 + lane];
#pragma unroll
    for (int q = 0; q < 8; q++) {
        int i = blockIdx.x * 32 + w * 8 + q;
        float d = a_dst[(size_t)bh * 1024 + i];
        float dm = d + sm;
        float m = dm > 0.f ? dm : NEG * dm;
        float c1 = __expf(dm - m);
        float c2 = __expf(NEG * dm - m);
        int e = (int)floorf((-d - mn) * scale + 0.5f);
        e = min(max(e, 0), NBUK);
        float P1f = 0.f, P2f = 0.f, z1f = 0.f, z2f = 0.f;
        if (e > 0) {
            size_t o = ((pb + e - 1) * 2) * 64 + lane;
            P1f = P[o]; P2f = P[o + 64];
            z1f = zb[(pb + e - 1) * 2];
            z2f = zb[(pb + e - 1) * 2 + 1];
        }
        float num = c1 * (T1 - P1f) + c2 * P2f;
        float Z = c1 * (z1tot - z1f) + c2 * z2f;
        gat[((size_t)(b * NS + i)) * ND + h * 64 + lane] = f2bf(num / Z + bias);
    }
}

// ---------------- GEMM core: 64x128 tile, BK=64, XOR chunk-swizzle, dbuf LDS ----------------
// T4 counted-vmcnt pipeline (R12-verified): wait vmcnt(6), raw s_barrier, compute, barrier, restage.
template <bool OUT_BF16, bool BIAS, bool DUAL, bool ATT>
static __device__ __forceinline__ void gemm_body(
    const unsigned short* __restrict__ A1, const unsigned short* __restrict__ B1,
    int lda1, int ldb1,
    const unsigned short* __restrict__ A2, const unsigned short* __restrict__ B2,
    int lda2, int ldb2,
    const float* __restrict__ bias, void* __restrict__ Cout,
    int m0, int n0, int N, int K,
    unsigned short* sA, unsigned short* sB,
    const float* __restrict__ att_src, const float* __restrict__ att_dst,
    float* __restrict__ a_src, float* __restrict__ a_dst) {
    int t = threadIdx.x, wave = t >> 6, lane = t & 63;
    int lr = lane & 15, kq = lane >> 4;
    int srow = t >> 3;                         // 0..31 staging row
    int scol = ((t & 7) ^ (srow & 7)) * 8;     // inverse-swizzled source chunk (shorts)
    int cs0 = ((kq) ^ (lr & 7)) * 8;           // kk=0 read chunk
    int cs1 = ((4 + kq) ^ (lr & 7)) * 8;       // kk=1 read chunk
    const int kh = K >> 6;
    const int nsteps = (DUAL ? 2 : 1) * kh;
    f32x4 acc[4][2] = {};

    auto STAGE = [&](int s, int buf) {
        const unsigned short* A; const unsigned short* Bt; int lda, ldb, k0;
        if (DUAL && s >= kh) { A = A2; Bt = B2; lda = lda2; ldb = ldb2; k0 = (s - kh) << 6; }
        else { A = A1; Bt = B1; lda = lda1; ldb = ldb1; k0 = s << 6; }
        const unsigned short* gA = A + (size_t)(m0 + srow) * lda + scol + k0;
        const unsigned short* gB = Bt + (size_t)(n0 + srow) * ldb + scol + k0;
        unsigned short* dA = sA + buf * 4096 + t * 8;
        unsigned short* dB = sB + buf * 8192 + t * 8;
        gload16(gA, dA);
        gload16(gA + (size_t)32 * lda, dA + 2048);
        gload16(gB, dB);
        gload16(gB + (size_t)32 * ldb, dB + 2048);
        gload16(gB + (size_t)64 * ldb, dB + 4096);
        gload16(gB + (size_t)96 * ldb, dB + 6144);
    };
    auto COMPUTE = [&](int cur) {
        unsigned short* cA = sA + cur * 4096;
        unsigned short* cB = sB + cur * 8192;
        bf16x8 a0[4], a1v[4], b0[2], b1v[2];
#pragma unroll
        for (int m = 0; m < 4; m++) {
            a0[m]  = *reinterpret_cast<bf16x8*>(&cA[(m * 16 + lr) * 64 + cs0]);
            a1v[m] = *reinterpret_cast<bf16x8*>(&cA[(m * 16 + lr) * 64 + cs1]);
        }
#pragma unroll
        for (int n = 0; n < 2; n++) {
            b0[n]  = *reinterpret_cast<bf16x8*>(&cB[(wave * 32 + n * 16 + lr) * 64 + cs0]);
            b1v[n] = *reinterpret_cast<bf16x8*>(&cB[(wave * 32 + n * 16 + lr) * 64 + cs1]);
        }
#pragma unroll
        for (int m = 0; m < 4; m++)
#pragma unroll
            for (int n = 0; n < 2; n++) {
                acc[m][n] = __builtin_amdgcn_mfma_f32_16x16x32_bf16(a0[m], b0[n], acc[m][n], 0, 0, 0);
                acc[m][n] = __builtin_amdgcn_mfma_f32_16x16x32_bf16(a1v[m], b1v[n], acc[m][n], 0, 0, 0);
            }
    };

    STAGE(0, 0);
    STAGE(1, 1);
    for (int s = 0; s < nsteps - 1; s++) {
        int cur = s & 1;
        asm volatile("s_waitcnt vmcnt(6)" ::: "memory");   // prior stage landed; 6 in flight
        __builtin_amdgcn_s_barrier();
        __builtin_amdgcn_sched_barrier(0);
        COMPUTE(cur);
        __builtin_amdgcn_sched_barrier(0);
        __builtin_amdgcn_s_barrier();                       // all waves done reading buf[cur]
        if (s + 2 < nsteps) STAGE(s + 2, cur);              // overwrite buf[cur]
    }
    asm volatile("s_waitcnt vmcnt(0)" ::: "memory");
    __builtin_amdgcn_s_barrier();
    __builtin_amdgcn_sched_barrier(0);
    COMPUTE((nsteps - 1) & 1);

    int rg = kq * 4;
#pragma unroll
    for (int m = 0; m < 4; m++) {
#pragma unroll
        for (int n = 0; n < 2; n++) {
            int col = n0 + wave * 32 + n * 16 + lr;
            float bv = BIAS ? bias[col] : 0.0f;
#pragma unroll
            for (int r = 0; r < 4; r++) {
                int row = m0 + m * 16 + rg + r;
                float v = acc[m][n][r] + bv;
                if (OUT_BF16) {
                    ((unsigned short*)Cout)[(size_t)row * N + col] = f2bf(v);
                } else {
                    ((float*)Cout)[(size_t)row * N + col] = v;
                }
            }
        }
    }

    if (ATT) {
        __syncthreads();   // all waves done with sA before scratch reuse
        float ds_[4][4] = {}, dd_[4][4] = {};
#pragma unroll
        for (int n = 0; n < 2; n++) {
            int colg = n0 + wave * 32 + n * 16 + lr;
            float as_v = att_src[colg];
            float ad_v = att_dst[colg];
#pragma unroll
            for (int m = 0; m < 4; m++)
#pragma unroll
                for (int r = 0; r < 4; r++) {
                    ds_[m][r] = fmaf(acc[m][n][r], as_v, ds_[m][r]);
                    dd_[m][r] = fmaf(acc[m][n][r], ad_v, dd_[m][r]);
                }
        }
#pragma unroll
        for (int off = 1; off <= 8; off <<= 1)
#pragma unroll
            for (int m = 0; m < 4; m++)
#pragma unroll
                for (int r = 0; r < 4; r++) {
                    ds_[m][r] += __shfl_xor(ds_[m][r], off, 64);
                    dd_[m][r] += __shfl_xor(dd_[m][r], off, 64);
                }
        float* red = (float*)sA;   // scratch, safe post-loop
        if (lr == 0) {
#pragma unroll
            for (int m = 0; m < 4; m++)
#pragma unroll
                for (int r = 0; r < 4; r++) {
                    int rl = m * 16 + kq * 4 + r;
                    red[wave * 64 + rl] = ds_[m][r];
                    red[256 + wave * 64 + rl] = dd_[m][r];
                }
        }
        __syncthreads();
        if (t < 128) {
            int hb = t >> 6, rl = t & 63;
            float vs = red[(hb * 2) * 64 + rl] + red[(hb * 2 + 1) * 64 + rl];
            float vd = red[256 + (hb * 2) * 64 + rl] + red[256 + (hb * 2 + 1) * 64 + rl];
            int grow = m0 + rl;
            int b = grow >> 10, sdx = grow & 1023;
            int head = (n0 >> 6) + hb;
            a_src[((size_t)b * NH + head) * NS + sdx] = vs;
            a_dst[((size_t)b * NH + head) * NS + sdx] = vd;
        }
    }
}

// two independent bf16-out GEMMs in one grid (gemm1 [+attn dots] + Wcomb)
__global__ __launch_bounds__(256) void k_gemm_pair(
    const unsigned short* __restrict__ Aa, const unsigned short* __restrict__ Ba,
    unsigned short* __restrict__ Ca, int NBna, int Na, int Ka, int lda_a, int ldb_a, int nwg_a,
    const unsigned short* __restrict__ Ab, const unsigned short* __restrict__ Bb,
    unsigned short* __restrict__ Cb, int NBnb, int Nb, int Kb, int lda_b, int ldb_b,
    const float* __restrict__ att_src, const float* __restrict__ att_dst,
    float* __restrict__ a_src, float* __restrict__ a_dst) {
    __shared__ alignas(16) unsigned short sA[2 * 64 * 64];
    __shared__ alignas(16) unsigned short sB[2 * 128 * 64];
    int wg = swz_bid(blockIdx.x, gridDim.x);
    if (wg < nwg_a) {
        gemm_body<true, false, false, true>(Aa, Ba, lda_a, ldb_a, nullptr, nullptr, 0, 0, nullptr,
                                            Ca, (wg / NBna) * 64, (wg % NBna) * 128, Na, Ka, sA, sB,
                                            att_src, att_dst, a_src, a_dst);
    } else {
        wg -= nwg_a;
        gemm_body<true, false, false, false>(Ab, Bb, lda_b, ldb_b, nullptr, nullptr, 0, 0, nullptr,
                                             Cb, (wg / NBnb) * 64, (wg % NBnb) * 128, Nb, Kb, sA, sB,
                                             nullptr, nullptr, nullptr, nullptr);
    }
}

// dual accumulating GEMM with fp32 out + bias
__global__ __launch_bounds__(256) void k_gemm_dual(
    const unsigned short* __restrict__ A1, const unsigned short* __restrict__ B1,
    const unsigned short* __restrict__ A2, const unsigned short* __restrict__ B2,
    const float* __restrict__ bias, float* __restrict__ out,
    int NBn, int N, int K, int lda, int ldb1, int ldb2) {
    __shared__ alignas(16) unsigned short sA[2 * 64 * 64];
    __shared__ alignas(16) unsigned short sB[2 * 128 * 64];
    int wg = swz_bid(blockIdx.x, gridDim.x);
    gemm_body<false, true, true, false>(A1, B1, lda, ldb1, A2, B2, lda, ldb2, bias,
                                        out, (wg / NBn) * 64, (wg % NBn) * 128, N, K, sA, sB,
                                        nullptr, nullptr, nullptr, nullptr);
}

extern "C" void kernel_launch(void* const* d_in, const int* in_sizes, int n_in,
                              void* d_out, int out_size, void* d_ws, size_t ws_size,
                              hipStream_t stream) {
    const float* hs  = (const float*)d_in[0];
    const float* to  = (const float*)d_in[1];
    const float* Wg  = (const float*)d_in[2];
    const float* asv = (const float*)d_in[3];
    const float* adv = (const float*)d_in[4];
    const float* bg  = (const float*)d_in[5];
    const float* Wp  = (const float*)d_in[6];
    const float* bp  = (const float*)d_in[7];
    const float* Wf  = (const float*)d_in[8];
    const float* bfu = (const float*)d_in[9];
    float* out = (float*)d_out;

    char* ws = (char*)d_ws;
    size_t off = 0;
    auto alloc = [&](size_t bytes) -> void* {
        void* p = ws + off;
        off = (off + bytes + 255) & ~(size_t)255;
        return p;
    };
    const size_t NBSD = (size_t)NB * NS * ND;
    const int NBH = NB * NH;
    unsigned short* h_bf   = (unsigned short*)alloc(NBSD * 2);  // later reused as gat_bf
    unsigned short* x_bf   = (unsigned short*)alloc(NBSD * 2);
    unsigned short* t_bf   = (unsigned short*)alloc(NBSD * 2);
    unsigned short* WgT    = (unsigned short*)alloc((size_t)ND * ND * 2);
    unsigned short* Wp_bf  = (unsigned short*)alloc((size_t)ND * ND * 2);
    unsigned short* WfT    = (unsigned short*)alloc((size_t)2 * ND * ND * 2);
    unsigned short* WcombT = (unsigned short*)alloc((size_t)ND * ND * 2);
    float*  bias_tot = (float*)alloc((size_t)ND * 4);
    float*  a_src = (float*)alloc((size_t)NBH * NS * 4);
    float*  a_dst = (float*)alloc((size_t)NBH * NS * 4);
    float4* pack  = (float4*)alloc((size_t)NBH * NS * 16);
    int*    bstart = (int*)alloc((size_t)NBH * (NBUK + 1) * 4);
    float*  P     = (float*)alloc((size_t)NBH * NBUK * 2 * 64 * 4);
    float*  zb    = (float*)alloc((size_t)NBH * NBUK * 2 * 4);
    float*  smaxb = (float*)alloc((size_t)NBH * 4);
    float2* bparam = (float2*)alloc((size_t)NBH * 8);

    int n1 = (int)NBSD / 4, n2 = ND * ND / 4;
    const int NT1 = (ND / 32) * (3 * ND / 32);
    const int NT2 = (ND * 8) / 256;
    const int NT3 = (2 * n1 + n2 + 255) / 256;
    k_prep<<<NT1 + NT2 + NT3, 256, 0, stream>>>(hs, to, Wp, Wg, Wf, bp, bfu,
                                                h_bf, t_bf, Wp_bf, WgT, WfT, bias_tot, n1, n2);

    // gemm1 (x = hs@W_gat, + attn dots) ; Wcomb: WcombT = (Wp @ Wf_bot)^T  — one grid, n-fastest
    int nwg1 = (NB * NS / 64) * (ND / 128);          // 576
    int nwgW = (ND / 64) * (ND / 128);               // 72
    k_gemm_pair<<<nwg1 + nwgW, 256, 0, stream>>>(
        h_bf, WgT, x_bf, ND / 128, ND, ND, ND, ND, nwg1,
        WfT + ND, Wp_bf, WcombT, ND / 128, ND, ND, 2 * ND, ND,
        asv, adv, a_src, a_dst);

    k_bucket<<<NBH, 256, 0, stream>>>(a_src, pack, bstart, smaxb, bparam, zb);
    k_bsum<<<dim3(NBUK / 8, NBH), 256, 0, stream>>>(x_bf, pack, bstart, P);
    k_bpref<<<NBH, 256, 0, stream>>>(P);

    unsigned short* gat_bf = h_bf;
    k_apply3<<<dim3(NS / 32, NBH), 256, 0, stream>>>(P, zb, a_dst, smaxb, bparam, bg, gat_bf);

    // out = t @ Wf_top + gat @ Wcomb + bias_tot
    k_gemm_dual<<<(NB * NS / 64) * (ND / 128), 256, 0, stream>>>(
        t_bf, WfT, gat_bf, WcombT, bias_tot, out, ND / 128, ND, ND, ND, 2 * ND, ND);
}

// Round 17
// 111.347 us; speedup vs baseline: 1.6938x; 1.0597x over previous
//
#include <hip/hip_runtime.h>
#include <hip/hip_bf16.h>

#define NB 8
#define NS 1024
#define ND 768
#define NH 12
#define NC 64
#define NEG 0.2f
#define NBUK 128

typedef __attribute__((ext_vector_type(8))) short bf16x8;
typedef __attribute__((ext_vector_type(4))) float f32x4;

static __device__ __forceinline__ float bf2f(unsigned short u) {
    union { float f; unsigned int i; } v; v.i = ((unsigned int)u) << 16; return v.f;
}
static __device__ __forceinline__ unsigned short f2bf(float f) {
    union { float f; unsigned int i; } v; v.f = f;
    unsigned int r = v.i + 0x7FFFu + ((v.i >> 16) & 1u);
    return (unsigned short)(r >> 16);
}

static __device__ __forceinline__ void gload16(const unsigned short* g, unsigned short* l) {
    __builtin_amdgcn_global_load_lds((const __attribute__((address_space(1))) void*)g,
                                     (__attribute__((address_space(3))) void*)l, 16, 0, 0);
}

// bijective XCD-chunk swizzle (m204)
static __device__ __forceinline__ int swz_bid(int orig, int nwg) {
    int q = nwg >> 3, r = nwg & 7;
    int xcd = orig & 7, idx = orig >> 3;
    return (xcd < r ? xcd * (q + 1) : r * (q + 1) + (xcd - r) * q) + idx;
}

// ---------------- prep: weight transposes + fp32->bf16 conversions + bias_tot ----------------
__global__ __launch_bounds__(256) void k_prep(const float* __restrict__ hs, const float* __restrict__ to,
                                              const float* __restrict__ Wp, const float* __restrict__ Wg,
                                              const float* __restrict__ Wf, const float* __restrict__ bp,
                                              const float* __restrict__ bfu,
                                              unsigned short* __restrict__ h_bf, unsigned short* __restrict__ t_bf,
                                              unsigned short* __restrict__ Wp_bf, unsigned short* __restrict__ WgT,
                                              unsigned short* __restrict__ WfT, float* __restrict__ bias_tot,
                                              int n1, int n2) {
    const int NT1 = (ND / 32) * (3 * ND / 32);   // 1728 transpose tiles
    const int NT2 = (ND * 8) / 256;              // 24 bias blocks
    int blk = blockIdx.x, t = threadIdx.x;
    if (blk < NT1) {
        __shared__ float tile[32][33];
        int bx = blk % (ND / 32), by = blk / (ND / 32);
        const float* src; unsigned short* dst; int K, k0;
        if (by < ND / 32) { src = Wg; dst = WgT; K = ND; k0 = by * 32; }
        else { src = Wf; dst = WfT; K = 2 * ND; k0 = (by - ND / 32) * 32; }
        int n0 = bx * 32;
        int r = t >> 3, c4 = (t & 7) * 4;
        float4 v = *reinterpret_cast<const float4*>(src + (size_t)(k0 + r) * ND + n0 + c4);
        tile[r][c4] = v.x; tile[r][c4 + 1] = v.y; tile[r][c4 + 2] = v.z; tile[r][c4 + 3] = v.w;
        __syncthreads();
        ushort4 o;
        o.x = f2bf(tile[c4][r]); o.y = f2bf(tile[c4 + 1][r]);
        o.z = f2bf(tile[c4 + 2][r]); o.w = f2bf(tile[c4 + 3][r]);
        *reinterpret_cast<ushort4*>(dst + (size_t)(n0 + r) * K + k0 + c4) = o;
    } else if (blk < NT1 + NT2) {
        int gid = (blk - NT1) * 256 + t;
        int c = gid >> 3, sl = gid & 7;
        float acc = 0.f;
        int k0 = sl * 96;
#pragma unroll 8
        for (int k = k0; k < k0 + 96; k++) acc += bp[k] * Wf[(size_t)(ND + k) * ND + c];
        acc += __shfl_down(acc, 1, 64);
        acc += __shfl_down(acc, 2, 64);
        acc += __shfl_down(acc, 4, 64);
        if (sl == 0) bias_tot[c] = acc + bfu[c];
    } else {
        int gid = (blk - NT1 - NT2) * 256 + t;
        const float* s; unsigned short* d; int i;
        if (gid < n1) { s = hs; d = h_bf; i = gid; }
        else if (gid < 2 * n1) { s = to; d = t_bf; i = gid - n1; }
        else { s = Wp; d = Wp_bf; i = gid - 2 * n1; if (i >= n2) return; }
        i *= 4;
        float4 v = *reinterpret_cast<const float4*>(s + i);
        ushort4 o;
        o.x = f2bf(v.x); o.y = f2bf(v.y); o.z = f2bf(v.z); o.w = f2bf(v.w);
        *reinterpret_cast<ushort4*>(d + i) = o;
    }
}

// ---------------- counting sort into NBUK buckets + fused z-prefix (once per bh) ----------------
__global__ __launch_bounds__(256) void k_bucket(const float* __restrict__ a_src,
                                                float4* __restrict__ pack,
                                                int* __restrict__ bstart,
                                                float* __restrict__ smax_g,
                                                float2* __restrict__ bparam,
                                                float* __restrict__ zb) {
    int bh = blockIdx.x, t = threadIdx.x;
    __shared__ float v[1024];
    __shared__ int bi[1024];
    __shared__ float red[256];
    __shared__ int cnt[NBUK], pre[NBUK];
    __shared__ float zs1[NBUK], zs2[NBUK];
    for (int i = t; i < 1024; i += 256) v[i] = a_src[(size_t)bh * 1024 + i];
    if (t < NBUK) { cnt[t] = 0; zs1[t] = 0.f; zs2[t] = 0.f; }
    __syncthreads();
    float lm = -1e30f, ln = 1e30f;
    for (int i = t; i < 1024; i += 256) { lm = fmaxf(lm, v[i]); ln = fminf(ln, v[i]); }
    red[t] = lm; __syncthreads();
    for (int s = 128; s > 0; s >>= 1) { if (t < s) red[t] = fmaxf(red[t], red[t + s]); __syncthreads(); }
    float mx = red[0]; __syncthreads();
    red[t] = ln; __syncthreads();
    for (int s = 128; s > 0; s >>= 1) { if (t < s) red[t] = fminf(red[t], red[t + s]); __syncthreads(); }
    float mn = red[0]; __syncthreads();
    float scale = (float)NBUK / fmaxf(mx - mn, 1e-20f);
    for (int i = t; i < 1024; i += 256) {
        int bk = (int)((v[i] - mn) * scale);
        bk = min(max(bk, 0), NBUK - 1);
        bi[i] = bk;
        atomicAdd(&cnt[bk], 1);
    }
    __syncthreads();
    if (t < NBUK) pre[t] = cnt[t];
    __syncthreads();
    for (int off = 1; off < NBUK; off <<= 1) {
        int x = (t >= off && t < NBUK) ? pre[t - off] : 0;
        __syncthreads();
        if (t < NBUK) pre[t] += x;
        __syncthreads();
    }
    if (t < NBUK) {
        int start = pre[t] - cnt[t];
        bstart[bh * (NBUK + 1) + t] = start;
        cnt[t] = start;
    }
    if (t == 0) {
        bstart[bh * (NBUK + 1) + NBUK] = 1024;
        smax_g[bh] = mx;
        bparam[bh] = make_float2(mn, scale);
    }
    __syncthreads();
    for (int i = t; i < 1024; i += 256) {
        int pos = atomicAdd(&cnt[bi[i]], 1);
        float u = v[i] - mx;
        float4 p;
        p.x = u; p.y = __expf(u); p.z = __expf(0.2f * u); p.w = __int_as_float(i);
        pack[(size_t)bh * 1024 + pos] = p;
        atomicAdd(&zs1[bi[i]], p.y);
        atomicAdd(&zs2[bi[i]], p.z);
    }
    __syncthreads();
    for (int off = 1; off < NBUK; off <<= 1) {
        float x1 = (t >= off && t < NBUK) ? zs1[t - off] : 0.f;
        float x2 = (t >= off && t < NBUK) ? zs2[t - off] : 0.f;
        __syncthreads();
        if (t < NBUK) { zs1[t] += x1; zs2[t] += x2; }
        __syncthreads();
    }
    if (t < NBUK) {
        zb[(size_t)(bh * NBUK + t) * 2] = zs1[t];
        zb[(size_t)(bh * NBUK + t) * 2 + 1] = zs2[t];
    }
}

// ---------------- per-bucket vector sums with 4-way ILP ----------------
__global__ __launch_bounds__(256) void k_bsum(const unsigned short* __restrict__ x_bf,
                                              const float4* __restrict__ pack,
                                              const int* __restrict__ bstart,
                                              float* __restrict__ P) {
    int grp = blockIdx.x, bh = blockIdx.y;
    int t = threadIdx.x, w = t >> 6, lane = t & 63;
    int b = bh / NH, h = bh % NH;
    const float4* pk = pack + (size_t)bh * 1024;
    const unsigned short* xb = x_bf + (size_t)b * NS * ND + h * 64 + lane;
#pragma unroll
    for (int r = 0; r < 2; r++) {
        int bk = grp * 8 + w * 2 + r;
        int ks = bstart[bh * (NBUK + 1) + bk], ke = bstart[bh * (NBUK + 1) + bk + 1];
        float V1p0 = 0.f, V1p1 = 0.f, V1p2 = 0.f, V1p3 = 0.f;
        float V2p0 = 0.f, V2p1 = 0.f, V2p2 = 0.f, V2p3 = 0.f;
        int k = ks;
        for (; k + 4 <= ke; k += 4) {
            float4 p0 = pk[k], p1 = pk[k + 1], p2 = pk[k + 2], p3 = pk[k + 3];
            float x0 = bf2f(xb[(size_t)__float_as_int(p0.w) * ND]);
            float x1 = bf2f(xb[(size_t)__float_as_int(p1.w) * ND]);
            float x2 = bf2f(xb[(size_t)__float_as_int(p2.w) * ND]);
            float x3 = bf2f(xb[(size_t)__float_as_int(p3.w) * ND]);
            V1p0 = fmaf(p0.y, x0, V1p0); V2p0 = fmaf(p0.z, x0, V2p0);
            V1p1 = fmaf(p1.y, x1, V1p1); V2p1 = fmaf(p1.z, x1, V2p1);
            V1p2 = fmaf(p2.y, x2, V1p2); V2p2 = fmaf(p2.z, x2, V2p2);
            V1p3 = fmaf(p3.y, x3, V1p3); V2p3 = fmaf(p3.z, x3, V2p3);
        }
        for (; k < ke; k++) {
            float4 p = pk[k];
            float xv = bf2f(xb[(size_t)__float_as_int(p.w) * ND]);
            V1p0 = fmaf(p.y, xv, V1p0); V2p0 = fmaf(p.z, xv, V2p0);
        }
        float V1 = (V1p0 + V1p1) + (V1p2 + V1p3);
        float V2 = (V2p0 + V2p1) + (V2p2 + V2p3);
        size_t o = ((size_t)(bh * NBUK + bk) * 2) * 64 + lane;
        P[o] = V1; P[o + 64] = V2;
    }
}

// ---------------- inclusive prefix over buckets for vectors P ----------------
__global__ __launch_bounds__(256) void k_bpref(float* __restrict__ P) {
    int bh = blockIdx.x, t = threadIdx.x, w = t >> 6, lane = t & 63;
    __shared__ float segV[4][2][64];
    size_t base = (size_t)bh * NBUK;
    float V1 = 0.f, V2 = 0.f;
    for (int g = 0; g < 4; ++g) {
        float a1[8], a2[8];
#pragma unroll
        for (int r = 0; r < 8; r++) {
            size_t o = ((base + w * 32 + g * 8 + r) * 2) * 64 + lane;
            a1[r] = P[o]; a2[r] = P[o + 64];
        }
#pragma unroll
        for (int r = 0; r < 8; r++) { V1 += a1[r]; a1[r] = V1; V2 += a2[r]; a2[r] = V2; }
#pragma unroll
        for (int r = 0; r < 8; r++) {
            size_t o = ((base + w * 32 + g * 8 + r) * 2) * 64 + lane;
            P[o] = a1[r]; P[o + 64] = a2[r];
        }
    }
    segV[w][0][lane] = V1; segV[w][1][lane] = V2;
    __syncthreads();
    if (w > 0) {
        float O1 = 0.f, O2 = 0.f;
        for (int w2 = 0; w2 < w; w2++) { O1 += segV[w2][0][lane]; O2 += segV[w2][1][lane]; }
        for (int g = 0; g < 4; ++g) {
            float a1[8], a2[8];
#pragma unroll
            for (int r = 0; r < 8; r++) {
                size_t o = ((base + w * 32 + g * 8 + r) * 2) * 64 + lane;
                a1[r] = P[o]; a2[r] = P[o + 64];
            }
#pragma unroll
            for (int r = 0; r < 8; r++) {
                size_t o = ((base + w * 32 + g * 8 + r) * 2) * 64 + lane;
                P[o] = a1[r] + O1; P[o + 64] = a2[r] + O2;
            }
        }
    }
}

// ---------------- apply: rounded-bucket-edge cutoff, pure prefix combine ----------------
__global__ __launch_bounds__(256) void k_apply3(const float* __restrict__ P,
                                                const float* __restrict__ zb,
                                                const float* __restrict__ a_dst,
                                                const float* __restrict__ smax_g,
                                                const float2* __restrict__ bparam,
                                                const float* __restrict__ b_gat,
                                                unsigned short* __restrict__ gat) {
    int bh = blockIdx.y, t = threadIdx.x, w = t >> 6, lane = t & 63;
    int b = bh / NH, h = bh % NH;
    float sm = smax_g[bh];
    float2 bp_ = bparam[bh];
    float mn = bp_.x, scale = bp_.y;
    size_t pb = (size_t)bh * NBUK;
    float T1 = P[((pb + NBUK - 1) * 2) * 64 + lane];
    float z1tot = zb[(pb + NBUK - 1) * 2];
    float bias = b_gat[h * 64 + lane];
#pragma unroll
    for (int q = 0; q < 8; q++) {
        int i = blockIdx.x * 32 + w * 8 + q;
        float d = a_dst[(size_t)bh * 1024 + i];
        float dm = d + sm;
        float m = dm > 0.f ? dm : NEG * dm;
        float c1 = __expf(dm - m);
        float c2 = __expf(NEG * dm - m);
        int e = (int)floorf((-d - mn) * scale + 0.5f);
        e = min(max(e, 0), NBUK);
        float P1f = 0.f, P2f = 0.f, z1f = 0.f, z2f = 0.f;
        if (e > 0) {
            size_t o = ((pb + e - 1) * 2) * 64 + lane;
            P1f = P[o]; P2f = P[o + 64];
            z1f = zb[(pb + e - 1) * 2];
            z2f = zb[(pb + e - 1) * 2 + 1];
        }
        float num = c1 * (T1 - P1f) + c2 * P2f;
        float Z = c1 * (z1tot - z1f) + c2 * z2f;
        gat[((size_t)(b * NS + i)) * ND + h * 64 + lane] = f2bf(num / Z + bias);
    }
}

// ---------------- GEMM core: 128x128 tile, BK=64, XOR chunk-swizzle, dbuf LDS ----------------
// 4 waves (2x2), each owns 64x64 -> 32 MFMA per 16 ds_read_b128 (1.5x LDS efficiency vs 64x128).
// counted-vmcnt depth-2 pipeline: wait vmcnt(8), barrier, compute, barrier, restage.
template <bool OUT_BF16, bool BIAS, bool DUAL, bool ATT>
static __device__ __forceinline__ void gemm_body(
    const unsigned short* __restrict__ A1, const unsigned short* __restrict__ B1,
    int lda1, int ldb1,
    const unsigned short* __restrict__ A2, const unsigned short* __restrict__ B2,
    int lda2, int ldb2,
    const float* __restrict__ bias, void* __restrict__ Cout,
    int m0, int n0, int N, int K,
    unsigned short* sA, unsigned short* sB,
    const float* __restrict__ att_src, const float* __restrict__ att_dst,
    float* __restrict__ a_src, float* __restrict__ a_dst) {
    int t = threadIdx.x, wave = t >> 6, lane = t & 63;
    int wm = wave >> 1, wn = wave & 1;
    int lr = lane & 15, kq = lane >> 4;
    int srow = t >> 3;                         // 0..31 staging row (per pass)
    int scol = ((t & 7) ^ (srow & 7)) * 8;     // inverse-swizzled source chunk (shorts)
    int cs0 = ((kq) ^ (lr & 7)) * 8;           // kk=0 read chunk
    int cs1 = ((4 + kq) ^ (lr & 7)) * 8;       // kk=1 read chunk
    const int kh = K >> 6;
    const int nsteps = (DUAL ? 2 : 1) * kh;
    f32x4 acc[4][4] = {};

    auto STAGE = [&](int s, int buf) {
        const unsigned short* A; const unsigned short* Bt; int lda, ldb, k0;
        if (DUAL && s >= kh) { A = A2; Bt = B2; lda = lda2; ldb = ldb2; k0 = (s - kh) << 6; }
        else { A = A1; Bt = B1; lda = lda1; ldb = ldb1; k0 = s << 6; }
        const unsigned short* gA = A + (size_t)(m0 + srow) * lda + scol + k0;
        const unsigned short* gB = Bt + (size_t)(n0 + srow) * ldb + scol + k0;
        unsigned short* dA = sA + buf * 8192 + t * 8;
        unsigned short* dB = sB + buf * 8192 + t * 8;
#pragma unroll
        for (int p = 0; p < 4; p++) {
            gload16(gA + (size_t)(p * 32) * lda, dA + p * 2048);
            gload16(gB + (size_t)(p * 32) * ldb, dB + p * 2048);
        }
    };
    auto COMPUTE = [&](int cur) {
        unsigned short* cA = sA + cur * 8192;
        unsigned short* cB = sB + cur * 8192;
        bf16x8 a0[4], a1v[4], b0[4], b1v[4];
#pragma unroll
        for (int m = 0; m < 4; m++) {
            a0[m]  = *reinterpret_cast<bf16x8*>(&cA[(wm * 64 + m * 16 + lr) * 64 + cs0]);
            a1v[m] = *reinterpret_cast<bf16x8*>(&cA[(wm * 64 + m * 16 + lr) * 64 + cs1]);
        }
#pragma unroll
        for (int n = 0; n < 4; n++) {
            b0[n]  = *reinterpret_cast<bf16x8*>(&cB[(wn * 64 + n * 16 + lr) * 64 + cs0]);
            b1v[n] = *reinterpret_cast<bf16x8*>(&cB[(wn * 64 + n * 16 + lr) * 64 + cs1]);
        }
#pragma unroll
        for (int m = 0; m < 4; m++)
#pragma unroll
            for (int n = 0; n < 4; n++) {
                acc[m][n] = __builtin_amdgcn_mfma_f32_16x16x32_bf16(a0[m], b0[n], acc[m][n], 0, 0, 0);
                acc[m][n] = __builtin_amdgcn_mfma_f32_16x16x32_bf16(a1v[m], b1v[n], acc[m][n], 0, 0, 0);
            }
    };

    STAGE(0, 0);
    STAGE(1, 1);
    for (int s = 0; s < nsteps - 1; s++) {
        int cur = s & 1;
        asm volatile("s_waitcnt vmcnt(8)" ::: "memory");   // stage s landed; s+1 (8 loads) in flight
        __builtin_amdgcn_s_barrier();
        __builtin_amdgcn_sched_barrier(0);
        COMPUTE(cur);
        __builtin_amdgcn_sched_barrier(0);
        __builtin_amdgcn_s_barrier();                       // all waves done reading buf[cur]
        if (s + 2 < nsteps) STAGE(s + 2, cur);              // overwrite buf[cur]
    }
    asm volatile("s_waitcnt vmcnt(0)" ::: "memory");
    __builtin_amdgcn_s_barrier();
    __builtin_amdgcn_sched_barrier(0);
    COMPUTE((nsteps - 1) & 1);

    int rg = kq * 4;
#pragma unroll
    for (int m = 0; m < 4; m++) {
#pragma unroll
        for (int n = 0; n < 4; n++) {
            int col = n0 + wn * 64 + n * 16 + lr;
            float bv = BIAS ? bias[col] : 0.0f;
#pragma unroll
            for (int r = 0; r < 4; r++) {
                int row = m0 + wm * 64 + m * 16 + rg + r;
                float v = acc[m][n][r] + bv;
                if (OUT_BF16) {
                    ((unsigned short*)Cout)[(size_t)row * N + col] = f2bf(v);
                } else {
                    ((float*)Cout)[(size_t)row * N + col] = v;
                }
            }
        }
    }

    if (ATT) {
        // wave covers exactly one head (64 cols) x 64 rows -> fully in-wave reduction
        int head = (n0 >> 6) + wn;
        float ds_[4][4] = {}, dd_[4][4] = {};
#pragma unroll
        for (int n = 0; n < 4; n++) {
            int colg = head * 64 + n * 16 + lr;
            float as_v = att_src[colg];
            float ad_v = att_dst[colg];
#pragma unroll
            for (int m = 0; m < 4; m++)
#pragma unroll
                for (int r = 0; r < 4; r++) {
                    ds_[m][r] = fmaf(acc[m][n][r], as_v, ds_[m][r]);
                    dd_[m][r] = fmaf(acc[m][n][r], ad_v, dd_[m][r]);
                }
        }
#pragma unroll
        for (int off = 1; off <= 8; off <<= 1)
#pragma unroll
            for (int m = 0; m < 4; m++)
#pragma unroll
                for (int r = 0; r < 4; r++) {
                    ds_[m][r] += __shfl_xor(ds_[m][r], off, 64);
                    dd_[m][r] += __shfl_xor(dd_[m][r], off, 64);
                }
        if (lr == 0) {
#pragma unroll
            for (int m = 0; m < 4; m++)
#pragma unroll
                for (int r = 0; r < 4; r++) {
                    int grow = m0 + wm * 64 + m * 16 + kq * 4 + r;
                    int b = grow >> 10, sdx = grow & 1023;
                    a_src[((size_t)b * NH + head) * NS + sdx] = ds_[m][r];
                    a_dst[((size_t)b * NH + head) * NS + sdx] = dd_[m][r];
                }
        }
    }
}

// two independent bf16-out GEMMs in one grid (gemm1 [+attn dots] + Wcomb)
__global__ __launch_bounds__(256) void k_gemm_pair(
    const unsigned short* __restrict__ Aa, const unsigned short* __restrict__ Ba,
    unsigned short* __restrict__ Ca, int NBna, int Na, int Ka, int lda_a, int ldb_a, int nwg_a,
    const unsigned short* __restrict__ Ab, const unsigned short* __restrict__ Bb,
    unsigned short* __restrict__ Cb, int NBnb, int Nb, int Kb, int lda_b, int ldb_b,
    const float* __restrict__ att_src, const float* __restrict__ att_dst,
    float* __restrict__ a_src, float* __restrict__ a_dst) {
    __shared__ alignas(16) unsigned short sA[2 * 128 * 64];
    __shared__ alignas(16) unsigned short sB[2 * 128 * 64];
    int wg = swz_bid(blockIdx.x, gridDim.x);
    if (wg < nwg_a) {
        gemm_body<true, false, false, true>(Aa, Ba, lda_a, ldb_a, nullptr, nullptr, 0, 0, nullptr,
                                            Ca, (wg / NBna) * 128, (wg % NBna) * 128, Na, Ka, sA, sB,
                                            att_src, att_dst, a_src, a_dst);
    } else {
        wg -= nwg_a;
        gemm_body<true, false, false, false>(Ab, Bb, lda_b, ldb_b, nullptr, nullptr, 0, 0, nullptr,
                                             Cb, (wg / NBnb) * 128, (wg % NBnb) * 128, Nb, Kb, sA, sB,
                                             nullptr, nullptr, nullptr, nullptr);
    }
}

// dual accumulating GEMM with fp32 out + bias
__global__ __launch_bounds__(256) void k_gemm_dual(
    const unsigned short* __restrict__ A1, const unsigned short* __restrict__ B1,
    const unsigned short* __restrict__ A2, const unsigned short* __restrict__ B2,
    const float* __restrict__ bias, float* __restrict__ out,
    int NBn, int N, int K, int lda, int ldb1, int ldb2) {
    __shared__ alignas(16) unsigned short sA[2 * 128 * 64];
    __shared__ alignas(16) unsigned short sB[2 * 128 * 64];
    int wg = swz_bid(blockIdx.x, gridDim.x);
    gemm_body<false, true, true, false>(A1, B1, lda, ldb1, A2, B2, lda, ldb2, bias,
                                        out, (wg / NBn) * 128, (wg % NBn) * 128, N, K, sA, sB,
                                        nullptr, nullptr, nullptr, nullptr);
}

extern "C" void kernel_launch(void* const* d_in, const int* in_sizes, int n_in,
                              void* d_out, int out_size, void* d_ws, size_t ws_size,
                              hipStream_t stream) {
    const float* hs  = (const float*)d_in[0];
    const float* to  = (const float*)d_in[1];
    const float* Wg  = (const float*)d_in[2];
    const float* asv = (const float*)d_in[3];
    const float* adv = (const float*)d_in[4];
    const float* bg  = (const float*)d_in[5];
    const float* Wp  = (const float*)d_in[6];
    const float* bp  = (const float*)d_in[7];
    const float* Wf  = (const float*)d_in[8];
    const float* bfu = (const float*)d_in[9];
    float* out = (float*)d_out;

    char* ws = (char*)d_ws;
    size_t off = 0;
    auto alloc = [&](size_t bytes) -> void* {
        void* p = ws + off;
        off = (off + bytes + 255) & ~(size_t)255;
        return p;
    };
    const size_t NBSD = (size_t)NB * NS * ND;
    const int NBH = NB * NH;
    unsigned short* h_bf   = (unsigned short*)alloc(NBSD * 2);  // later reused as gat_bf
    unsigned short* x_bf   = (unsigned short*)alloc(NBSD * 2);
    unsigned short* t_bf   = (unsigned short*)alloc(NBSD * 2);
    unsigned short* WgT    = (unsigned short*)alloc((size_t)ND * ND * 2);
    unsigned short* Wp_bf  = (unsigned short*)alloc((size_t)ND * ND * 2);
    unsigned short* WfT    = (unsigned short*)alloc((size_t)2 * ND * ND * 2);
    unsigned short* WcombT = (unsigned short*)alloc((size_t)ND * ND * 2);
    float*  bias_tot = (float*)alloc((size_t)ND * 4);
    float*  a_src = (float*)alloc((size_t)NBH * NS * 4);
    float*  a_dst = (float*)alloc((size_t)NBH * NS * 4);
    float4* pack  = (float4*)alloc((size_t)NBH * NS * 16);
    int*    bstart = (int*)alloc((size_t)NBH * (NBUK + 1) * 4);
    float*  P     = (float*)alloc((size_t)NBH * NBUK * 2 * 64 * 4);
    float*  zb    = (float*)alloc((size_t)NBH * NBUK * 2 * 4);
    float*  smaxb = (float*)alloc((size_t)NBH * 4);
    float2* bparam = (float2*)alloc((size_t)NBH * 8);

    int n1 = (int)NBSD / 4, n2 = ND * ND / 4;
    const int NT1 = (ND / 32) * (3 * ND / 32);
    const int NT2 = (ND * 8) / 256;
    const int NT3 = (2 * n1 + n2 + 255) / 256;
    k_prep<<<NT1 + NT2 + NT3, 256, 0, stream>>>(hs, to, Wp, Wg, Wf, bp, bfu,
                                                h_bf, t_bf, Wp_bf, WgT, WfT, bias_tot, n1, n2);

    // gemm1 (x = hs@W_gat, + attn dots) ; Wcomb: WcombT = (Wp @ Wf_bot)^T  — one grid
    int nwg1 = (NB * NS / 128) * (ND / 128);         // 288
    int nwgW = (ND / 128) * (ND / 128);              // 36
    k_gemm_pair<<<nwg1 + nwgW, 256, 0, stream>>>(
        h_bf, WgT, x_bf, ND / 128, ND, ND, ND, ND, nwg1,
        WfT + ND, Wp_bf, WcombT, ND / 128, ND, ND, 2 * ND, ND,
        asv, adv, a_src, a_dst);

    k_bucket<<<NBH, 256, 0, stream>>>(a_src, pack, bstart, smaxb, bparam, zb);
    k_bsum<<<dim3(NBUK / 8, NBH), 256, 0, stream>>>(x_bf, pack, bstart, P);
    k_bpref<<<NBH, 256, 0, stream>>>(P);

    unsigned short* gat_bf = h_bf;
    k_apply3<<<dim3(NS / 32, NBH), 256, 0, stream>>>(P, zb, a_dst, smaxb, bparam, bg, gat_bf);

    // out = t @ Wf_top + gat @ Wcomb + bias_tot
    k_gemm_dual<<<(NB * NS / 128) * (ND / 128), 256, 0, stream>>>(
        t_bf, WfT, gat_bf, WcombT, bias_tot, out, ND / 128, ND, ND, ND, 2 * ND, ND);
}